// Round 10
// baseline (762.140 us; speedup 1.0000x reference)
//
#include <hip/hip_runtime.h>

#define N 8192
#define DIM 256
#define QB 32             // queries per q-tile
#define NW 4              // waves per block (256 threads)
#define CB (NW*16)        // candidates per iteration = 64
#define SLICES 4          // candidate-dimension split
#define CPS (N / SLICES)  // candidates per slice = 2048
#define NIT (CPS / CB)    // 32
#define LK 33             // need 32nd and 33rd NN
#define NBIN 256          // histogram bins over d^2 in [0, 1024), width 4
#define BUFCAP 128        // per-query global candidate buffer
#define NFRAG 16          // 2 row-tiles x 8 k-steps

typedef short bf16x8 __attribute__((ext_vector_type(8)));
typedef float f32x4 __attribute__((ext_vector_type(4)));

static __device__ inline unsigned short f2bf(float f) {
    unsigned int u = __float_as_uint(f);
    unsigned int r = (u + 0x7fffu + ((u >> 16) & 1u)) >> 16;
    return (unsigned short)r;
}

// identical d^2 arithmetic in both passes (bit-exact across kernels; no fast-math)
static __device__ inline float dist2(float qn_plus_cn, float acc) {
    return __builtin_fmaf(-2.0f, acc, qn_plus_cn);
}

// ---------------- Kernel A: norms (fp32) + bf16 cast ----------------
__global__ __launch_bounds__(64) void prep_kernel(const float* __restrict__ feat,
                                                  unsigned short* __restrict__ fb,
                                                  float* __restrict__ norms) {
    int row = blockIdx.x;
    int lane = threadIdx.x;
    float4 v = reinterpret_cast<const float4*>(feat + (size_t)row * DIM)[lane];
    float ss = v.x * v.x + v.y * v.y + v.z * v.z + v.w * v.w;
    #pragma unroll
    for (int off = 32; off > 0; off >>= 1) ss += __shfl_xor(ss, off);
    if (lane == 0) norms[row] = ss;
    ushort4 b;
    b.x = f2bf(v.x); b.y = f2bf(v.y); b.z = f2bf(v.z); b.w = f2bf(v.w);
    reinterpret_cast<ushort4*>(fb + (size_t)row * DIM)[lane] = b;
}

// A-fragments in LDS per-lane layout (R3-R5: allocator won't keep them in regs)
#define STAGE_AQ_TO_LDS()                                                    \
    int koff = (lane >> 4) * 8;                                              \
    if (w == 0) {                                                            \
        int arow = qbase + (lane & 15);                                      \
        _Pragma("unroll")                                                    \
        for (int rt = 0; rt < 2; rt++) {                                     \
            _Pragma("unroll")                                                \
            for (int ks = 0; ks < 8; ks++)                                   \
                aLds[(rt * 8 + ks) * 64 + lane] =                            \
                    *reinterpret_cast<const bf16x8*>(                        \
                        fb + (size_t)(arow + rt * 16) * DIM + ks * 32 + koff); \
        }                                                                    \
    }

// ---------------- Pass 1: partial per-query d^2 histogram ----------------
// grid: 1024 blocks = qtile*4 + slice. Each block: 32 queries x 2048 candidates.
__global__ __launch_bounds__(NW * 64, 4) void hist_part_kernel(
    const unsigned short* __restrict__ fb, const float* __restrict__ norms,
    unsigned char* __restrict__ histp) {
    __shared__ bf16x8 aLds[NFRAG * 64];              // 16 KB
    __shared__ unsigned int hist[QB][NBIN / 2 + 1];  // packed 2 bins/word, 16.5 KB
    __shared__ float qn[QB];

    int tid = threadIdx.x;
    int w = tid >> 6;
    int lane = tid & 63;
    int qt = blockIdx.x >> 2;
    int slice = blockIdx.x & 3;
    int qbase = qt * QB;
    int cand0 = slice * CPS;

    for (int i = tid; i < QB * (NBIN / 2 + 1); i += NW * 64)
        (&hist[0][0])[i] = 0u;
    if (tid < QB) qn[tid] = norms[qbase + tid];

    STAGE_AQ_TO_LDS()
    __syncthreads();

    float qnr[2][4];
    unsigned int* hrow[2][4];
    int qgl[2][4];
    #pragma unroll
    for (int rt = 0; rt < 2; rt++)
        #pragma unroll
        for (int j = 0; j < 4; j++) {
            int ql = rt * 16 + (lane >> 4) * 4 + j;
            qnr[rt][j] = qn[ql];
            hrow[rt][j] = &hist[ql][0];
            qgl[rt][j] = qbase + ql;
        }

    int cbase = cand0 + w * 16 + (lane & 15);

    for (int it = 0; it < NIT; it++) {
        int crow = cbase + it * CB;
        const bf16x8* bp = reinterpret_cast<const bf16x8*>(
            fb + (size_t)crow * DIM + koff);
        bf16x8 bq[8];
        #pragma unroll
        for (int ks = 0; ks < 8; ks++) bq[ks] = bp[ks * 4];
        float cn = norms[crow];

        f32x4 acc[2][2] = {{{0.f,0.f,0.f,0.f},{0.f,0.f,0.f,0.f}},
                           {{0.f,0.f,0.f,0.f},{0.f,0.f,0.f,0.f}}};
        #pragma unroll
        for (int ks = 0; ks < 8; ks++) {
            bf16x8 a0 = aLds[ks * 64 + lane];
            bf16x8 a1 = aLds[(8 + ks) * 64 + lane];
            acc[0][ks & 1] = __builtin_amdgcn_mfma_f32_16x16x32_bf16(a0, bq[ks], acc[0][ks & 1], 0, 0, 0);
            acc[1][ks & 1] = __builtin_amdgcn_mfma_f32_16x16x32_bf16(a1, bq[ks], acc[1][ks & 1], 0, 0, 0);
        }

        #pragma unroll
        for (int rt = 0; rt < 2; rt++) {
            f32x4 s = acc[rt][0] + acc[rt][1];
            #pragma unroll
            for (int j = 0; j < 4; j++) {
                float d2 = dist2(qnr[rt][j] + cn, s[j]);
                if (crow != qgl[rt][j]) {
                    int b = (int)(d2 * 0.25f);
                    b = b < 0 ? 0 : (b > NBIN - 1 ? NBIN - 1 : b);
                    atomicAdd(&hrow[rt][j][b >> 1], 1u << ((b & 1) * 16));
                }
            }
        }
    }
    __syncthreads();

    // flush partial histogram (plain stores, u8 with safe saturation: any bin
    // at/below the 33rd-NN bin holds <50 counts; saturation above it is harmless)
    for (int i = tid; i < QB * NBIN; i += NW * 64) {
        int q = i >> 8, b = i & 255;
        unsigned int h = hist[q][b >> 1];
        unsigned int c = (h >> ((b & 1) * 16)) & 0xffffu;
        histp[(size_t)blockIdx.x * (QB * NBIN) + i] =
            (unsigned char)(c > 255u ? 255u : c);
    }
}

// ---------------- threshold: sum 4 partials, scan to 33rd ----------------
__global__ __launch_bounds__(256) void thresh_kernel(
    const unsigned char* __restrict__ histp, float* __restrict__ tq) {
    int q = blockIdx.x * 256 + threadIdx.x;
    int qt = q >> 5, ql = q & 31;
    const unsigned char* base = histp + (size_t)(qt * 4) * (QB * NBIN) + ql * NBIN;
    int cum = 0;
    int bstar = NBIN - 1;
    for (int b = 0; b < NBIN; b++) {
        cum += (int)base[b] + (int)base[QB * NBIN + b]
             + (int)base[2 * QB * NBIN + b] + (int)base[3 * QB * NBIN + b];
        if (cum >= LK) { bstar = b; break; }
    }
    tq[q] = (float)(bstar + 1) * 4.0f;  // upper edge: guarantees >=33 pass d2<T
}

// ---------------- Pass 2: collect d^2 < T into global per-query buffers ----------------
__global__ __launch_bounds__(NW * 64, 4) void collect_part_kernel(
    const unsigned short* __restrict__ fb, const float* __restrict__ norms,
    const float* __restrict__ tq, unsigned int* __restrict__ cnt,
    float* __restrict__ cand_d, int* __restrict__ cand_i) {
    __shared__ bf16x8 aLds[NFRAG * 64];  // 16 KB
    __shared__ float qn[QB];
    __shared__ float Tsh[QB];

    int tid = threadIdx.x;
    int w = tid >> 6;
    int lane = tid & 63;
    int qt = blockIdx.x >> 2;
    int slice = blockIdx.x & 3;
    int qbase = qt * QB;
    int cand0 = slice * CPS;

    if (tid < QB) {
        qn[tid] = norms[qbase + tid];
        Tsh[tid] = tq[qbase + tid];
    }

    STAGE_AQ_TO_LDS()
    __syncthreads();

    float qnr[2][4], Tr[2][4];
    int qgl[2][4];
    #pragma unroll
    for (int rt = 0; rt < 2; rt++)
        #pragma unroll
        for (int j = 0; j < 4; j++) {
            int ql = rt * 16 + (lane >> 4) * 4 + j;
            qnr[rt][j] = qn[ql];
            Tr[rt][j] = Tsh[ql];
            qgl[rt][j] = qbase + ql;
        }

    int cbase = cand0 + w * 16 + (lane & 15);

    for (int it = 0; it < NIT; it++) {
        int crow = cbase + it * CB;
        const bf16x8* bp = reinterpret_cast<const bf16x8*>(
            fb + (size_t)crow * DIM + koff);
        bf16x8 bq[8];
        #pragma unroll
        for (int ks = 0; ks < 8; ks++) bq[ks] = bp[ks * 4];
        float cn = norms[crow];

        f32x4 acc[2][2] = {{{0.f,0.f,0.f,0.f},{0.f,0.f,0.f,0.f}},
                           {{0.f,0.f,0.f,0.f},{0.f,0.f,0.f,0.f}}};
        #pragma unroll
        for (int ks = 0; ks < 8; ks++) {
            bf16x8 a0 = aLds[ks * 64 + lane];
            bf16x8 a1 = aLds[(8 + ks) * 64 + lane];
            acc[0][ks & 1] = __builtin_amdgcn_mfma_f32_16x16x32_bf16(a0, bq[ks], acc[0][ks & 1], 0, 0, 0);
            acc[1][ks & 1] = __builtin_amdgcn_mfma_f32_16x16x32_bf16(a1, bq[ks], acc[1][ks & 1], 0, 0, 0);
        }

        #pragma unroll
        for (int rt = 0; rt < 2; rt++) {
            f32x4 s = acc[rt][0] + acc[rt][1];
            #pragma unroll
            for (int j = 0; j < 4; j++) {
                float d2 = dist2(qnr[rt][j] + cn, s[j]);
                if (crow != qgl[rt][j] && d2 < Tr[rt][j]) {
                    int qg = qgl[rt][j];
                    unsigned int slot = atomicAdd(&cnt[qg], 1u);  // device-scope
                    if (slot < BUFCAP) {
                        cand_d[(size_t)qg * BUFCAP + slot] = d2;
                        cand_i[(size_t)qg * BUFCAP + slot] = crow;
                    }
                }
            }
        }
    }
}

// ---------------- select: exact top-33 per query, scratch-free ----------------
// Iterative rank extraction under lexicographic (d2, idx) order: deterministic
// regardless of the nondeterministic slot order, matches stable argsort.
__global__ __launch_bounds__(256) void select_kernel(
    const unsigned int* __restrict__ cnt,
    const float* __restrict__ cand_d, const int* __restrict__ cand_i,
    float* __restrict__ kd32sq, float* __restrict__ kd33sq, int* __restrict__ knn) {
    int q = blockIdx.x * 256 + threadIdx.x;
    int n = (int)cnt[q]; if (n > BUFCAP) n = BUFCAP;
    const float* cd = cand_d + (size_t)q * BUFCAP;
    const int*  ci = cand_i + (size_t)q * BUFCAP;
    float pd = -3.0e38f; int pi = -1;
    float d32 = 0.0f, d33 = 0.0f;
    for (int r = 0; r < LK; r++) {
        float bd = 3.0e38f; int bi = 0x7fffffff;
        for (int t = 0; t < n; t++) {
            float d = cd[t]; int ix = ci[t];
            bool gt_prev = (d > pd) || (d == pd && ix > pi);
            bool lt_cur  = (d < bd) || (d == bd && ix < bi);
            if (gt_prev && lt_cur) { bd = d; bi = ix; }
        }
        if (bi > N - 1) { bi = 0; bd = 1.0f; }  // safety (never hit: n>=33 by construction)
        if (r < 32) knn[(size_t)q * 32 + r] = bi;
        if (r == 31) d32 = bd;
        if (r == 32) d33 = bd;
        pd = bd; pi = bi;
    }
    kd32sq[q] = d32;
    kd33sq[q] = d33;
}

// ---------------- scores ----------------
__global__ __launch_bounds__(256) void scores_kernel(
    const float* __restrict__ kd32sq, const float* __restrict__ kd33sq,
    const int* __restrict__ knn, float* __restrict__ out) {
    int i = blockIdx.x * blockDim.x + threadIdx.x;
    float num = sqrtf(fmaxf(kd33sq[i], 0.0f));
    float s = 0.0f;
    #pragma unroll
    for (int t = 0; t < 32; t++) {
        int j = knn[(size_t)i * 32 + t];
        int m = j - (j > i);  // reference indexes a_full_d rows with reduced index
        float den = sqrtf(fmaxf(kd32sq[m], 0.0f));
        s += num / den;
    }
    s *= (1.0f / 32.0f);
    if (isnan(s)) s = 1000.0f;
    else if (isinf(s)) s = (s > 0.0f) ? 1000.0f : 0.0f;
    out[i] = s;
}

extern "C" void kernel_launch(void* const* d_in, const int* in_sizes, int n_in,
                              void* d_out, int out_size, void* d_ws, size_t ws_size,
                              hipStream_t stream) {
    (void)in_sizes; (void)n_in; (void)out_size; (void)ws_size;
    const float* feat = (const float*)d_in[0];

    char* ws = (char*)d_ws;
    size_t off = 0;
    unsigned short* fb = (unsigned short*)(ws + off); off += (size_t)N * DIM * 2;      // 4 MB
    float* norms = (float*)(ws + off); off += (size_t)N * 4;                            // 32 KB
    float* tqv   = (float*)(ws + off); off += (size_t)N * 4;                            // 32 KB
    float* kd32  = (float*)(ws + off); off += (size_t)N * 4;                            // 32 KB
    float* kd33  = (float*)(ws + off); off += (size_t)N * 4;                            // 32 KB
    int*   knn   = (int*)(ws + off); off += (size_t)N * 32 * 4;                         // 1 MB
    unsigned int* cnt = (unsigned int*)(ws + off); off += (size_t)N * 4;                // 32 KB
    float* cand_d = (float*)(ws + off); off += (size_t)N * BUFCAP * 4;                  // 4 MB
    int*   cand_i = (int*)(ws + off); off += (size_t)N * BUFCAP * 4;                    // 4 MB
    unsigned char* histp = (unsigned char*)(ws + off); off += (size_t)(N/QB)*SLICES*QB*NBIN; // 8 MB

    hipMemsetAsync(cnt, 0, (size_t)N * 4, stream);
    prep_kernel<<<N, 64, 0, stream>>>(feat, fb, norms);
    hist_part_kernel<<<(N / QB) * SLICES, NW * 64, 0, stream>>>(fb, norms, histp);
    thresh_kernel<<<N / 256, 256, 0, stream>>>(histp, tqv);
    collect_part_kernel<<<(N / QB) * SLICES, NW * 64, 0, stream>>>(fb, norms, tqv, cnt, cand_d, cand_i);
    select_kernel<<<N / 256, 256, 0, stream>>>(cnt, cand_d, cand_i, kd32, kd33, knn);
    scores_kernel<<<N / 256, 256, 0, stream>>>(kd32, kd33, knn, (float*)d_out);
}

// Round 11
// 370.777 us; speedup vs baseline: 2.0555x; 2.0555x over previous
//
#include <hip/hip_runtime.h>

#define N 8192
#define DIM 256
#define QB 32             // queries per q-tile
#define NW 4              // waves per block (256 threads)
#define CB (NW*16)        // candidates per iteration = 64
#define SLICES 4          // candidate-dimension split
#define CPS (N / SLICES)  // candidates per slice = 2048
#define NIT (CPS / CB)    // 32
#define LK 33             // need 32nd and 33rd NN
#define NBIN 256          // histogram bins over d^2 in [0, 1024), width 4
#define BUFCAP 128        // per-query global candidate buffer
#define NFRAG 16          // 2 row-tiles x 8 k-steps

typedef short bf16x8 __attribute__((ext_vector_type(8)));
typedef float f32x4 __attribute__((ext_vector_type(4)));

static __device__ inline unsigned short f2bf(float f) {
    unsigned int u = __float_as_uint(f);
    unsigned int r = (u + 0x7fffu + ((u >> 16) & 1u)) >> 16;
    return (unsigned short)r;
}

// identical d^2 arithmetic in both passes (bit-exact across kernels; no fast-math)
static __device__ inline float dist2(float qn_plus_cn, float acc) {
    return __builtin_fmaf(-2.0f, acc, qn_plus_cn);
}

// ---------------- Kernel A: norms (fp32) + bf16 cast ----------------
__global__ __launch_bounds__(64) void prep_kernel(const float* __restrict__ feat,
                                                  unsigned short* __restrict__ fb,
                                                  float* __restrict__ norms) {
    int row = blockIdx.x;
    int lane = threadIdx.x;
    float4 v = reinterpret_cast<const float4*>(feat + (size_t)row * DIM)[lane];
    float ss = v.x * v.x + v.y * v.y + v.z * v.z + v.w * v.w;
    #pragma unroll
    for (int off = 32; off > 0; off >>= 1) ss += __shfl_xor(ss, off);
    if (lane == 0) norms[row] = ss;
    ushort4 b;
    b.x = f2bf(v.x); b.y = f2bf(v.y); b.z = f2bf(v.z); b.w = f2bf(v.w);
    reinterpret_cast<ushort4*>(fb + (size_t)row * DIM)[lane] = b;
}

// A-fragments in LDS per-lane layout (R3-R5: allocator won't keep them in regs)
#define STAGE_AQ_TO_LDS()                                                    \
    int koff = (lane >> 4) * 8;                                              \
    if (w == 0) {                                                            \
        int arow = qbase + (lane & 15);                                      \
        _Pragma("unroll")                                                    \
        for (int rt = 0; rt < 2; rt++) {                                     \
            _Pragma("unroll")                                                \
            for (int ks = 0; ks < 8; ks++)                                   \
                aLds[(rt * 8 + ks) * 64 + lane] =                            \
                    *reinterpret_cast<const bf16x8*>(                        \
                        fb + (size_t)(arow + rt * 16) * DIM + ks * 32 + koff); \
        }                                                                    \
    }

// ---------------- Pass 1: partial per-query d^2 histogram ----------------
// grid: 1024 blocks = qtile*4 + slice. Each block: 32 queries x 2048 candidates.
__global__ __launch_bounds__(NW * 64, 4) void hist_part_kernel(
    const unsigned short* __restrict__ fb, const float* __restrict__ norms,
    unsigned char* __restrict__ histp) {
    __shared__ bf16x8 aLds[NFRAG * 64];              // 16 KB
    __shared__ unsigned int hist[QB][NBIN / 2 + 1];  // packed 2 bins/word, 16.5 KB
    __shared__ float qn[QB];

    int tid = threadIdx.x;
    int w = tid >> 6;
    int lane = tid & 63;
    int qt = blockIdx.x >> 2;
    int slice = blockIdx.x & 3;
    int qbase = qt * QB;
    int cand0 = slice * CPS;

    for (int i = tid; i < QB * (NBIN / 2 + 1); i += NW * 64)
        (&hist[0][0])[i] = 0u;
    if (tid < QB) qn[tid] = norms[qbase + tid];

    STAGE_AQ_TO_LDS()
    __syncthreads();

    float qnr[2][4];
    unsigned int* hrow[2][4];
    int qgl[2][4];
    #pragma unroll
    for (int rt = 0; rt < 2; rt++)
        #pragma unroll
        for (int j = 0; j < 4; j++) {
            int ql = rt * 16 + (lane >> 4) * 4 + j;
            qnr[rt][j] = qn[ql];
            hrow[rt][j] = &hist[ql][0];
            qgl[rt][j] = qbase + ql;
        }

    int cbase = cand0 + w * 16 + (lane & 15);

    for (int it = 0; it < NIT; it++) {
        int crow = cbase + it * CB;
        const bf16x8* bp = reinterpret_cast<const bf16x8*>(
            fb + (size_t)crow * DIM + koff);
        bf16x8 bq[8];
        #pragma unroll
        for (int ks = 0; ks < 8; ks++) bq[ks] = bp[ks * 4];
        float cn = norms[crow];

        f32x4 acc[2][2] = {{{0.f,0.f,0.f,0.f},{0.f,0.f,0.f,0.f}},
                           {{0.f,0.f,0.f,0.f},{0.f,0.f,0.f,0.f}}};
        #pragma unroll
        for (int ks = 0; ks < 8; ks++) {
            bf16x8 a0 = aLds[ks * 64 + lane];
            bf16x8 a1 = aLds[(8 + ks) * 64 + lane];
            acc[0][ks & 1] = __builtin_amdgcn_mfma_f32_16x16x32_bf16(a0, bq[ks], acc[0][ks & 1], 0, 0, 0);
            acc[1][ks & 1] = __builtin_amdgcn_mfma_f32_16x16x32_bf16(a1, bq[ks], acc[1][ks & 1], 0, 0, 0);
        }

        #pragma unroll
        for (int rt = 0; rt < 2; rt++) {
            f32x4 s = acc[rt][0] + acc[rt][1];
            #pragma unroll
            for (int j = 0; j < 4; j++) {
                float d2 = dist2(qnr[rt][j] + cn, s[j]);
                if (crow != qgl[rt][j]) {
                    int b = (int)(d2 * 0.25f);
                    b = b < 0 ? 0 : (b > NBIN - 1 ? NBIN - 1 : b);
                    atomicAdd(&hrow[rt][j][b >> 1], 1u << ((b & 1) * 16));
                }
            }
        }
    }
    __syncthreads();

    // flush partial histogram (plain stores, u8 with safe saturation: any bin
    // at/below the 33rd-NN bin holds <50 counts; saturation above it is harmless)
    for (int i = tid; i < QB * NBIN; i += NW * 64) {
        int q = i >> 8, b = i & 255;
        unsigned int h = hist[q][b >> 1];
        unsigned int c = (h >> ((b & 1) * 16)) & 0xffffu;
        histp[(size_t)blockIdx.x * (QB * NBIN) + i] =
            (unsigned char)(c > 255u ? 255u : c);
    }
}

// ---------------- threshold: sum 4 partials, scan to 33rd ----------------
__global__ __launch_bounds__(256) void thresh_kernel(
    const unsigned char* __restrict__ histp, float* __restrict__ tq) {
    int q = blockIdx.x * 256 + threadIdx.x;
    int qt = q >> 5, ql = q & 31;
    const unsigned char* base = histp + (size_t)(qt * 4) * (QB * NBIN) + ql * NBIN;
    int cum = 0;
    int bstar = NBIN - 1;
    for (int b = 0; b < NBIN; b++) {
        cum += (int)base[b] + (int)base[QB * NBIN + b]
             + (int)base[2 * QB * NBIN + b] + (int)base[3 * QB * NBIN + b];
        if (cum >= LK) { bstar = b; break; }
    }
    tq[q] = (float)(bstar + 1) * 4.0f;  // upper edge: guarantees >=33 pass d2<T
}

// ---------------- Pass 2: collect d^2 < T into global per-query buffers ----------------
__global__ __launch_bounds__(NW * 64, 4) void collect_part_kernel(
    const unsigned short* __restrict__ fb, const float* __restrict__ norms,
    const float* __restrict__ tq, unsigned int* __restrict__ cnt,
    float* __restrict__ cand_d, int* __restrict__ cand_i) {
    __shared__ bf16x8 aLds[NFRAG * 64];  // 16 KB
    __shared__ float qn[QB];
    __shared__ float Tsh[QB];

    int tid = threadIdx.x;
    int w = tid >> 6;
    int lane = tid & 63;
    int qt = blockIdx.x >> 2;
    int slice = blockIdx.x & 3;
    int qbase = qt * QB;
    int cand0 = slice * CPS;

    if (tid < QB) {
        qn[tid] = norms[qbase + tid];
        Tsh[tid] = tq[qbase + tid];
    }

    STAGE_AQ_TO_LDS()
    __syncthreads();

    float qnr[2][4], Tr[2][4];
    int qgl[2][4];
    #pragma unroll
    for (int rt = 0; rt < 2; rt++)
        #pragma unroll
        for (int j = 0; j < 4; j++) {
            int ql = rt * 16 + (lane >> 4) * 4 + j;
            qnr[rt][j] = qn[ql];
            Tr[rt][j] = Tsh[ql];
            qgl[rt][j] = qbase + ql;
        }

    int cbase = cand0 + w * 16 + (lane & 15);

    for (int it = 0; it < NIT; it++) {
        int crow = cbase + it * CB;
        const bf16x8* bp = reinterpret_cast<const bf16x8*>(
            fb + (size_t)crow * DIM + koff);
        bf16x8 bq[8];
        #pragma unroll
        for (int ks = 0; ks < 8; ks++) bq[ks] = bp[ks * 4];
        float cn = norms[crow];

        f32x4 acc[2][2] = {{{0.f,0.f,0.f,0.f},{0.f,0.f,0.f,0.f}},
                           {{0.f,0.f,0.f,0.f},{0.f,0.f,0.f,0.f}}};
        #pragma unroll
        for (int ks = 0; ks < 8; ks++) {
            bf16x8 a0 = aLds[ks * 64 + lane];
            bf16x8 a1 = aLds[(8 + ks) * 64 + lane];
            acc[0][ks & 1] = __builtin_amdgcn_mfma_f32_16x16x32_bf16(a0, bq[ks], acc[0][ks & 1], 0, 0, 0);
            acc[1][ks & 1] = __builtin_amdgcn_mfma_f32_16x16x32_bf16(a1, bq[ks], acc[1][ks & 1], 0, 0, 0);
        }

        #pragma unroll
        for (int rt = 0; rt < 2; rt++) {
            f32x4 s = acc[rt][0] + acc[rt][1];
            #pragma unroll
            for (int j = 0; j < 4; j++) {
                float d2 = dist2(qnr[rt][j] + cn, s[j]);
                if (crow != qgl[rt][j] && d2 < Tr[rt][j]) {
                    int qg = qgl[rt][j];
                    unsigned int slot = atomicAdd(&cnt[qg], 1u);  // device-scope
                    if (slot < BUFCAP) {
                        cand_d[(size_t)qg * BUFCAP + slot] = d2;
                        cand_i[(size_t)qg * BUFCAP + slot] = crow;
                    }
                }
            }
        }
    }
}

// ---------------- select: exact top-33, ONE WAVE PER QUERY ----------------
// R10 lesson: per-thread serial O(33*n) scan at 32 blocks = 432 us, 1.4% occ.
// Now: 64-bit key = (monotonic_bits(d2) << 32) | idx; unsigned order == the
// lexicographic (d2, idx) order (stable-argsort-equivalent). Each lane owns 2
// of the 128 slots; 33 rounds of 6-step __shfl_xor u64 min + owner retire.
__global__ __launch_bounds__(256) void select_kernel(
    const unsigned int* __restrict__ cnt,
    const float* __restrict__ cand_d, const int* __restrict__ cand_i,
    float* __restrict__ kd32sq, float* __restrict__ kd33sq, int* __restrict__ knn) {
    int wid = threadIdx.x >> 6;
    int lane = threadIdx.x & 63;
    int q = blockIdx.x * 4 + wid;
    int n = (int)cnt[q]; if (n > BUFCAP) n = BUFCAP;
    const float* cd = cand_d + (size_t)q * BUFCAP;
    const int*   ci = cand_i + (size_t)q * BUFCAP;

    unsigned long long k0 = ~0ULL, k1 = ~0ULL;
    if (lane < n) {
        unsigned int b = __float_as_uint(cd[lane]);
        unsigned int t = b ^ ((b >> 31) ? 0xFFFFFFFFu : 0x80000000u);
        k0 = ((unsigned long long)t << 32) | (unsigned int)ci[lane];
    }
    if (lane + 64 < n) {
        unsigned int b = __float_as_uint(cd[lane + 64]);
        unsigned int t = b ^ ((b >> 31) ? 0xFFFFFFFFu : 0x80000000u);
        k1 = ((unsigned long long)t << 32) | (unsigned int)ci[lane + 64];
    }

    float d32 = 0.0f, d33 = 0.0f;
    for (int r = 0; r < LK; r++) {
        unsigned long long m = k0 < k1 ? k0 : k1;
        #pragma unroll
        for (int off = 32; off > 0; off >>= 1) {
            unsigned long long o = __shfl_xor(m, off);
            if (o < m) m = o;
        }
        unsigned int hi = (unsigned int)(m >> 32);
        unsigned int bb = (hi & 0x80000000u) ? (hi ^ 0x80000000u) : ~hi;
        float d = __uint_as_float(bb);
        int idx = (int)(m & 0xFFFFFFFFu);
        if (m == ~0ULL) { idx = 0; d = 1.0f; }  // safety (n>=33 by construction)
        if (lane == 0 && r < 32) knn[(size_t)q * 32 + r] = idx;
        if (r == 31) d32 = d;
        if (r == 32) d33 = d;
        if (k0 == m) k0 = ~0ULL; else if (k1 == m) k1 = ~0ULL;
    }
    if (lane == 0) { kd32sq[q] = d32; kd33sq[q] = d33; }
}

// ---------------- scores ----------------
__global__ __launch_bounds__(256) void scores_kernel(
    const float* __restrict__ kd32sq, const float* __restrict__ kd33sq,
    const int* __restrict__ knn, float* __restrict__ out) {
    int i = blockIdx.x * blockDim.x + threadIdx.x;
    float num = sqrtf(fmaxf(kd33sq[i], 0.0f));
    float s = 0.0f;
    #pragma unroll
    for (int t = 0; t < 32; t++) {
        int j = knn[(size_t)i * 32 + t];
        int m = j - (j > i);  // reference indexes a_full_d rows with reduced index
        float den = sqrtf(fmaxf(kd32sq[m], 0.0f));
        s += num / den;
    }
    s *= (1.0f / 32.0f);
    if (isnan(s)) s = 1000.0f;
    else if (isinf(s)) s = (s > 0.0f) ? 1000.0f : 0.0f;
    out[i] = s;
}

extern "C" void kernel_launch(void* const* d_in, const int* in_sizes, int n_in,
                              void* d_out, int out_size, void* d_ws, size_t ws_size,
                              hipStream_t stream) {
    (void)in_sizes; (void)n_in; (void)out_size; (void)ws_size;
    const float* feat = (const float*)d_in[0];

    char* ws = (char*)d_ws;
    size_t off = 0;
    unsigned short* fb = (unsigned short*)(ws + off); off += (size_t)N * DIM * 2;      // 4 MB
    float* norms = (float*)(ws + off); off += (size_t)N * 4;                            // 32 KB
    float* tqv   = (float*)(ws + off); off += (size_t)N * 4;                            // 32 KB
    float* kd32  = (float*)(ws + off); off += (size_t)N * 4;                            // 32 KB
    float* kd33  = (float*)(ws + off); off += (size_t)N * 4;                            // 32 KB
    int*   knn   = (int*)(ws + off); off += (size_t)N * 32 * 4;                         // 1 MB
    unsigned int* cnt = (unsigned int*)(ws + off); off += (size_t)N * 4;                // 32 KB
    float* cand_d = (float*)(ws + off); off += (size_t)N * BUFCAP * 4;                  // 4 MB
    int*   cand_i = (int*)(ws + off); off += (size_t)N * BUFCAP * 4;                    // 4 MB
    unsigned char* histp = (unsigned char*)(ws + off); off += (size_t)(N/QB)*SLICES*QB*NBIN; // 8 MB

    hipMemsetAsync(cnt, 0, (size_t)N * 4, stream);
    prep_kernel<<<N, 64, 0, stream>>>(feat, fb, norms);
    hist_part_kernel<<<(N / QB) * SLICES, NW * 64, 0, stream>>>(fb, norms, histp);
    thresh_kernel<<<N / 256, 256, 0, stream>>>(histp, tqv);
    collect_part_kernel<<<(N / QB) * SLICES, NW * 64, 0, stream>>>(fb, norms, tqv, cnt, cand_d, cand_i);
    select_kernel<<<N / 4, 256, 0, stream>>>(cnt, cand_d, cand_i, kd32, kd33, knn);
    scores_kernel<<<N / 256, 256, 0, stream>>>(kd32, kd33, knn, (float*)d_out);
}